// Round 19
// baseline (88.511 us; speedup 1.0000x reference)
//
#include <hip/hip_runtime.h>
#include <hip/hip_bf16.h>
#include <stdint.h>

#define NHEADS 12
#define HDIM   64
#define NB     4
#define SQ     1024
#define DM     768
#define NROWS  (NB*SQ)      // 4096
#define NWE    (DM*DM)      // 589824
#define NXE    (NROWS*DM)   // 3145728
#define NXV    (NXE/4)      // 786432
#define NWV    (NWE/4)      // 147456

typedef __attribute__((ext_vector_type(8))) short short8;
typedef __attribute__((ext_vector_type(4))) float f32x4;

__device__ __forceinline__ unsigned short f2bf(float f) {
  union { float f; unsigned u; } v; v.f = f;
  return (unsigned short)((v.u + 0x7fffu + ((v.u >> 16) & 1u)) >> 16);
}

// hardware bf16 pair pack (v_cvt_pk_bf16_f32 class, RNE — same rounding as f2bf)
__device__ __forceinline__ unsigned pkbf(float lo, float hi) {
  __hip_bfloat162 h;
  h.x = __float2bfloat16(lo);
  h.y = __float2bfloat16(hi);
  return *reinterpret_cast<unsigned*>(&h);
}

__device__ __forceinline__ void gload16(const void* g, void* l) {
  __builtin_amdgcn_global_load_lds((__attribute__((address_space(1))) void*)(void*)g,
                                   (__attribute__((address_space(3))) void*)l, 16, 0, 0);
}

// explicit DMA drain: the compiler does NOT emit vmcnt(0) at barriers whose
// global_load_lds were issued before a loop back-edge (v6 race, round 7/8).
__device__ __forceinline__ void drain_dma() {
  asm volatile("s_waitcnt vmcnt(0)" ::: "memory");
  __builtin_amdgcn_sched_barrier(0);
}

// ---------------- prep: vectorized fp32 -> bf16 + box centers ----------------
__global__ __launch_bounds__(256) void prep_kernel(
    const float* __restrict__ x, const float* __restrict__ Wq, const float* __restrict__ Wk,
    const float* __restrict__ Wv, const float* __restrict__ Wo, const float* __restrict__ boxes,
    unsigned short* __restrict__ xb, unsigned short* __restrict__ wcat,
    unsigned short* __restrict__ wob, float2* __restrict__ centers) {
  int i = blockIdx.x * 256 + threadIdx.x;
  if (i < NXV) {
    float4 v = ((const float4*)x)[i];
    ushort4 o;
    o.x = f2bf(v.x); o.y = f2bf(v.y); o.z = f2bf(v.z); o.w = f2bf(v.w);
    ((ushort4*)xb)[i] = o;
    return;
  }
  i -= NXV;
  if (i < NWV) {
    float4 q = ((const float4*)Wq)[i];
    float4 k = ((const float4*)Wk)[i];
    float4 v = ((const float4*)Wv)[i];
    float4 o = ((const float4*)Wo)[i];
    ushort4 t;
    t.x = f2bf(q.x); t.y = f2bf(q.y); t.z = f2bf(q.z); t.w = f2bf(q.w);
    ((ushort4*)wcat)[i] = t;
    t.x = f2bf(k.x); t.y = f2bf(k.y); t.z = f2bf(k.z); t.w = f2bf(k.w);
    ((ushort4*)(wcat + NWE))[i] = t;
    t.x = f2bf(v.x); t.y = f2bf(v.y); t.z = f2bf(v.z); t.w = f2bf(v.w);
    ((ushort4*)(wcat + 2 * NWE))[i] = t;
    t.x = f2bf(o.x); t.y = f2bf(o.y); t.z = f2bf(o.z); t.w = f2bf(o.w);
    ((ushort4*)wob)[i] = t;
    return;
  }
  i -= NWV;
  if (i < NROWS) {
    float4 bx = ((const float4*)boxes)[i];
    centers[i] = make_float2((bx.x + bx.z) * 0.5f, (bx.y + bx.w) * 0.5f);
  }
}

// ---------------- NT GEMM: C[M,N] = A[M,K] * B[N,K]^T  (bf16 in, fp32 acc) ----
template <int EPI, int BM, int BN>
__global__ __launch_bounds__(256, 2) void gemm_bt(
    const unsigned short* __restrict__ A, const unsigned short* __restrict__ Bw,
    int K, int tiles_n,
    const float* __restrict__ b0, const float* __restrict__ b1, const float* __restrict__ b2,
    unsigned short* __restrict__ outQ, unsigned short* __restrict__ outK,
    unsigned short* __restrict__ outVt, float* __restrict__ outF) {
  constexpr int MF = BM / 32, NF = BN / 32;
  __shared__ unsigned short lA[2][BM * 32];
  __shared__ unsigned short lB[2][BN * 32];
  const int tid = threadIdx.x, wave = tid >> 6, lane = tid & 63;
  const int tm = blockIdx.x / tiles_n, tn = blockIdx.x % tiles_n;
  const int wr = wave >> 1, wc = wave & 1;
  const int g = lane >> 4, c16 = lane & 15, kb8 = g * 8;

  f32x4 acc[MF][NF];
#pragma unroll
  for (int m = 0; m < MF; m++)
#pragma unroll
    for (int n = 0; n < NF; n++) acc[m][n] = (f32x4){0.f, 0.f, 0.f, 0.f};

  const unsigned short* Abase = A + (size_t)tm * BM * K;
  const unsigned short* Bbase = Bw + (size_t)tn * BN * K;
  const int srow = lane >> 2, scb = (lane & 3) << 4;

  auto stage = [&](int kt, int s) {
#pragma unroll
    for (int c = wave; c < BM / 16; c += 4)
      gload16((const char*)(Abase + (size_t)(c * 16 + srow) * K + kt) + scb,
              (char*)lA[s] + c * 1024);
#pragma unroll
    for (int c = wave; c < BN / 16; c += 4)
      gload16((const char*)(Bbase + (size_t)(c * 16 + srow) * K + kt) + scb,
              (char*)lB[s] + c * 1024);
  };

  stage(0, 0);
  const int nk = K >> 5;
#pragma unroll 1
  for (int i = 0; i < nk; i++) {
    drain_dma();
    __syncthreads();
    if (i + 1 < nk) stage((i + 1) * 32, (i + 1) & 1);
    const unsigned short* sA = lA[i & 1];
    const unsigned short* sB = lB[i & 1];
    short8 a[MF], b[NF];
#pragma unroll
    for (int m = 0; m < MF; m++)
      a[m] = *(const short8*)&sA[(wr * (BM / 2) + m * 16 + c16) * 32 + kb8];
#pragma unroll
    for (int n = 0; n < NF; n++)
      b[n] = *(const short8*)&sB[(wc * (BN / 2) + n * 16 + c16) * 32 + kb8];
#pragma unroll
    for (int m = 0; m < MF; m++)
#pragma unroll
      for (int n = 0; n < NF; n++)
        acc[m][n] = __builtin_amdgcn_mfma_f32_16x16x32_bf16(a[m], b[n], acc[m][n], 0, 0, 0);
  }

  // C/D layout (m89): col = lane&15, row = (lane>>4)*4 + r
#pragma unroll
  for (int m = 0; m < MF; m++) {
    const int gm0 = tm * BM + wr * (BM / 2) + m * 16 + g * 4;
    const int bb = gm0 >> 10, ss0 = gm0 & 1023;
#pragma unroll
    for (int n = 0; n < NF; n++) {
      const int gn = tn * BN + wc * (BN / 2) + n * 16 + c16;
      if (EPI == 0) {
        const int which = gn / DM, nn = gn - which * DM;
        const int h = nn >> 6, dh = nn & 63;
        const float bias = (which == 0 ? b0 : which == 1 ? b1 : b2)[nn];
        const float scale = (which == 0) ? 0.1803368801f : 1.0f;  // 0.125*log2e
        if (which == 2) {
          ushort4 pk;
          pk.x = f2bf(acc[m][n][0] + bias);
          pk.y = f2bf(acc[m][n][1] + bias);
          pk.z = f2bf(acc[m][n][2] + bias);
          pk.w = f2bf(acc[m][n][3] + bias);
          *(ushort4*)&outVt[(((size_t)bb * NHEADS + h) * HDIM + dh) * SQ + ss0] = pk;
        } else {
          unsigned short* dst = (which == 0 ? outQ : outK) + ((size_t)bb * NHEADS + h) * SQ * HDIM;
#pragma unroll
          for (int r = 0; r < 4; r++)
            dst[(size_t)(ss0 + r) * HDIM + dh] = f2bf((acc[m][n][r] + bias) * scale);
        }
      } else {
        const float bias = b0[gn];
#pragma unroll
        for (int r = 0; r < 4; r++)
          outF[(size_t)(gm0 + r) * DM + gn] = acc[m][n][r] + bias;
      }
    }
  }
}

// ---------------- fused spatial attention v13 (4 blocks/CU occupancy) --------
// Round-16 v7 structure with LDS trimmed to EXACTLY 40960 B = 160KiB/4:
//  - XOR-swizzled K/V double-buffers (proven fastest layout): 32 KB
//  - slice-major P (v9-proven, conflict-free, no padding): 8 KB
//  - centers direct from global (r17-proven neutral): 0 KB
// __launch_bounds__(256,4): 4 blocks/CU -> 16 waves/CU (+33% TLP for the
// dependency-chain-stall-bound loop). No scheduling/sync changes.
#define KVB  64
#define NT   (SQ / KVB)  // 16 tiles
__global__ __launch_bounds__(256, 4) void attn_kernel(
    const unsigned short* __restrict__ Qb, const unsigned short* __restrict__ Kb,
    const unsigned short* __restrict__ Vt, const float2* __restrict__ centers,
    const float* __restrict__ sbias, unsigned short* __restrict__ attb) {
  __shared__ unsigned short lK[2][KVB * HDIM];  // 2 x 8 KB, [64 rows][128 B] swizzled
  __shared__ unsigned short lV[2][HDIM * KVB];  // 2 x 8 KB, [64 rows][128 B] swizzled
  __shared__ unsigned short plds[4][16 * KVB];  // 8 KB, slice-major (total 40960)
  const int tid = threadIdx.x, wave = tid >> 6, lane = tid & 63;
  const int g = lane >> 4, c16 = lane & 15, kb8 = g * 8;
  const int bid = blockIdx.x;
  const int xcd = bid & 7, li = bid >> 3;       // li in 0..95
  const int bh = xcd * 6 + (li >> 4);
  const int qt = li & 15;
  const int b = bh / NHEADS, h = bh - b * NHEADS;
  const float sb = sbias[h] * 1.44269504f;      // exp2-domain bias coefficient

  const unsigned short* Qh = Qb + (size_t)bh * SQ * HDIM;
  const char* Kc = (const char*)(Kb + (size_t)bh * SQ * HDIM);  // K row = 128 B
  const char* Vc = (const char*)(Vt + (size_t)bh * HDIM * SQ);  // V row = 2048 B
  const float2* cent_g = centers + b * SQ;

  // staging lane terms (swizzle pre-applied to global source, rule #21)
  const int l8 = lane >> 3, l7 = lane & 7;      // 8 rows x 128 B per 1KB chunk
  const int swizL = (l7 * 16) ^ (l8 << 4);

  // stage one 64-token tile into buffer s: K 8 chunks, V 8 chunks (2/wave each)
  auto stage = [&](int tbn, int s) {
    const char* kbase = Kc + (size_t)tbn * 128;
#pragma unroll
    for (int j = 0; j < 2; j++) {
      const int i = wave * 2 + j;
      gload16(kbase + i * 1024 + l8 * 128 + swizL, (char*)lK[s] + i * 1024);
    }
    const char* vbase = Vc + (size_t)tbn * 2;
#pragma unroll
    for (int j = 0; j < 2; j++) {
      const int i = wave * 2 + j;
      gload16(vbase + (size_t)(i * 8 + l8) * 2048 + swizL, (char*)lV[s] + i * 1024);
    }
  };

  const int q = qt * 64 + wave * 16 + c16;      // this lane's q-row
  short8 qf[2];
  qf[0] = *(const short8*)&Qh[(size_t)q * HDIM + kb8];
  qf[1] = *(const short8*)&Qh[(size_t)q * HDIM + 32 + kb8];
  const float2 cq = cent_g[q];

  float mreg = -1e30f, lreg = 0.f;              // lreg: per-lane partial sum
  f32x4 oacc[4];
#pragma unroll
  for (int dd = 0; dd < 4; dd++) oacc[dd] = (f32x4){0.f, 0.f, 0.f, 0.f};

  stage(0, 0);

  const int swk = (c16 & 7) << 4;               // read-side swizzle key
#pragma unroll 1
  for (int t = 0; t < NT; t++) {
    const int cur = t & 1;
    const int tb = t * KVB;
    drain_dma();      // buf[cur] landed (all waves after barrier)
    __syncthreads();
    if (t + 1 < NT) stage((t + 1) * KVB, cur ^ 1);  // overlaps with compute
    // --- 1. QK^T from lK (swizzled b128 reads) ---
    f32x4 sv[4];
#pragma unroll
    for (int cc = 0; cc < 4; cc++) {
      const int rb = (cc * 16 + c16) * 128;
      short8 k0 = *(const short8*)((const char*)lK[cur] + rb + ((g * 16) ^ swk));
      short8 k1 = *(const short8*)((const char*)lK[cur] + rb + ((64 + g * 16) ^ swk));
      f32x4 s = (f32x4){0.f, 0.f, 0.f, 0.f};
      s = __builtin_amdgcn_mfma_f32_16x16x32_bf16(k0, qf[0], s, 0, 0, 0);
      s = __builtin_amdgcn_mfma_f32_16x16x32_bf16(k1, qf[1], s, 0, 0, 0);
      sv[cc] = s;
    }
    // --- 2. spatial bias from global centers (broadcast, L2-hot) ---
#pragma unroll
    for (int cc = 0; cc < 4; cc++) {
      const float4* cp = (const float4*)&cent_g[tb + cc * 16 + g * 4];
      float4 c01 = cp[0], c23 = cp[1];
      float dx, dy;
      dx = cq.x - c01.x; dy = cq.y - c01.y;
      sv[cc][0] -= __builtin_amdgcn_sqrtf(dx * dx + dy * dy) * sb;
      dx = cq.x - c01.z; dy = cq.y - c01.w;
      sv[cc][1] -= __builtin_amdgcn_sqrtf(dx * dx + dy * dy) * sb;
      dx = cq.x - c23.x; dy = cq.y - c23.y;
      sv[cc][2] -= __builtin_amdgcn_sqrtf(dx * dx + dy * dy) * sb;
      dx = cq.x - c23.z; dy = cq.y - c23.w;
      sv[cc][3] -= __builtin_amdgcn_sqrtf(dx * dx + dy * dy) * sb;
    }
    // --- 3. defer-max online softmax (no shfl in common path) ---
    float lm = -1e30f;
#pragma unroll
    for (int cc = 0; cc < 4; cc++) {
      float a0 = fmaxf(sv[cc][0], sv[cc][1]), a1 = fmaxf(sv[cc][2], sv[cc][3]);
      lm = fmaxf(lm, fmaxf(a0, a1));
    }
    if (!__all(lm <= mreg + 8.0f)) {
      float vmax = fmaxf(lm, __shfl_xor(lm, 16));
      vmax = fmaxf(vmax, __shfl_xor(vmax, 32));
      const float mn = fmaxf(mreg, vmax);
      const float sc = __builtin_amdgcn_exp2f(mreg - mn);
      lreg *= sc;
#pragma unroll
      for (int dd = 0; dd < 4; dd++)
#pragma unroll
        for (int r = 0; r < 4; r++) oacc[dd][r] *= sc;
      mreg = mn;
    }
    float ps = 0.f;
#pragma unroll
    for (int cc = 0; cc < 4; cc++)
#pragma unroll
      for (int r = 0; r < 4; r++) {
        sv[cc][r] = __builtin_amdgcn_exp2f(sv[cc][r] - mreg);
        ps += sv[cc][r];
      }
    lreg += ps;
    // --- 4. P -> per-wave LDS, slice-major (v9-proven, conflict-free) ---
    char* P0 = (char*)&plds[wave][0];
#pragma unroll
    for (int cc = 0; cc < 4; cc++) {
      uint2 u;
      u.x = pkbf(sv[cc][0], sv[cc][1]);
      u.y = pkbf(sv[cc][2], sv[cc][3]);
      *(uint2*)(P0 + (cc * 2 + (g >> 1)) * 256 + c16 * 16 + (g & 1) * 8) = u;
    }
    // --- 5. PV from lV (XOR-swizzled) + plds (slice-major) ---
#pragma unroll
    for (int kc = 0; kc < 2; kc++) {
      short8 pf = *(const short8*)(P0 + (kc * 4 + g) * 256 + c16 * 16);
#pragma unroll
      for (int dd = 0; dd < 4; dd++) {
        short8 vf = *(const short8*)((const char*)lV[cur] + (dd * 16 + c16) * 128 +
                                     ((kc * 64 + g * 16) ^ swk));
        oacc[dd] = __builtin_amdgcn_mfma_f32_16x16x32_bf16(vf, pf, oacc[dd], 0, 0, 0);
      }
    }
  }
  // --- epilogue: reduce l across the 4 row-group lanes, write O ---
  lreg += __shfl_xor(lreg, 16);
  lreg += __shfl_xor(lreg, 32);
  const float inv = 1.f / lreg;
#pragma unroll
  for (int dd = 0; dd < 4; dd++) {
    uint2 u;
    u.x = pkbf(oacc[dd][0] * inv, oacc[dd][1] * inv);
    u.y = pkbf(oacc[dd][2] * inv, oacc[dd][3] * inv);
    *(uint2*)&attb[(size_t)(b * SQ + q) * DM + h * HDIM + dd * 16 + g * 4] = u;
  }
}

// ---------------- host-side launch ----------------
extern "C" void kernel_launch(void* const* d_in, const int* in_sizes, int n_in,
                              void* d_out, int out_size, void* d_ws, size_t ws_size,
                              hipStream_t stream) {
  const float* x     = (const float*)d_in[0];
  const float* boxes = (const float*)d_in[1];
  const float* Wq    = (const float*)d_in[2];
  const float* bq    = (const float*)d_in[3];
  const float* Wk    = (const float*)d_in[4];
  const float* bk    = (const float*)d_in[5];
  const float* Wv    = (const float*)d_in[6];
  const float* bv    = (const float*)d_in[7];
  const float* Wo    = (const float*)d_in[8];
  const float* bo    = (const float*)d_in[9];
  const float* sb    = (const float*)d_in[10];

  char* ws = (char*)d_ws;
  unsigned short* xb   = (unsigned short*)(ws);             // 6291456 B
  unsigned short* wcat = (unsigned short*)(ws + 6291456);   // 3538944 B
  unsigned short* wob  = (unsigned short*)(ws + 9830400);   // 1179648 B
  unsigned short* qb   = (unsigned short*)(ws + 11010048);  // 6291456 B
  unsigned short* kb   = (unsigned short*)(ws + 17301504);  // 6291456 B
  unsigned short* vtb  = (unsigned short*)(ws + 23592960);  // 6291456 B
  unsigned short* attb = (unsigned short*)(ws + 29884416);  // 6291456 B
  float2* centers      = (float2*)(ws + 36175872);          // 32768 B  (total ~36.2 MB)
  float* out = (float*)d_out;

  // vectorized prep: (NXV + NWV + NROWS) / 256 = 937984/256 = 3664 blocks
  prep_kernel<<<3664, 256, 0, stream>>>(x, Wq, Wk, Wv, Wo, boxes, xb, wcat, wob, centers);
  // 128x96 tiles: N=2304=24x96 -> grid 32*24=768 = exactly 3 blocks/CU, balanced
  gemm_bt<0, 128, 96><<<32 * 24, 256, 0, stream>>>(xb, wcat, DM, 24, bq, bk, bv,
                                                   qb, kb, vtb, nullptr);
  attn_kernel<<<768, 256, 0, stream>>>(qb, kb, vtb, centers, sb, attb);
  gemm_bt<1, 64, 64><<<64 * 12, 256, 0, stream>>>(attb, wob, DM, 12, bo, nullptr, nullptr,
                                                  nullptr, nullptr, nullptr, out);
}

// Round 20
// 87.346 us; speedup vs baseline: 1.0133x; 1.0133x over previous
//
#include <hip/hip_runtime.h>
#include <hip/hip_bf16.h>
#include <stdint.h>

#define NHEADS 12
#define HDIM   64
#define NB     4
#define SQ     1024
#define DM     768
#define NROWS  (NB*SQ)      // 4096
#define NWE    (DM*DM)      // 589824
#define NXE    (NROWS*DM)   // 3145728
#define NXV    (NXE/4)      // 786432
#define NWV    (NWE/4)      // 147456

typedef __attribute__((ext_vector_type(8))) short short8;
typedef __attribute__((ext_vector_type(4))) float f32x4;

__device__ __forceinline__ unsigned short f2bf(float f) {
  union { float f; unsigned u; } v; v.f = f;
  return (unsigned short)((v.u + 0x7fffu + ((v.u >> 16) & 1u)) >> 16);
}

// hardware bf16 pair pack (v_cvt_pk_bf16_f32 class, RNE — same rounding as f2bf)
__device__ __forceinline__ unsigned pkbf(float lo, float hi) {
  __hip_bfloat162 h;
  h.x = __float2bfloat16(lo);
  h.y = __float2bfloat16(hi);
  return *reinterpret_cast<unsigned*>(&h);
}

__device__ __forceinline__ void gload16(const void* g, void* l) {
  __builtin_amdgcn_global_load_lds((__attribute__((address_space(1))) void*)(void*)g,
                                   (__attribute__((address_space(3))) void*)l, 16, 0, 0);
}

// explicit DMA drain: the compiler does NOT emit vmcnt(0) at barriers whose
// global_load_lds were issued before a loop back-edge (v6 race, round 7/8).
__device__ __forceinline__ void drain_dma() {
  asm volatile("s_waitcnt vmcnt(0)" ::: "memory");
  __builtin_amdgcn_sched_barrier(0);
}

// ---------------- prep: vectorized fp32 -> bf16 + box centers ----------------
// G13: float4 loads (16B/lane) + ushort4 packed stores; 4 elems/thread.
__global__ __launch_bounds__(256) void prep_kernel(
    const float* __restrict__ x, const float* __restrict__ Wq, const float* __restrict__ Wk,
    const float* __restrict__ Wv, const float* __restrict__ Wo, const float* __restrict__ boxes,
    unsigned short* __restrict__ xb, unsigned short* __restrict__ wcat,
    unsigned short* __restrict__ wob, float2* __restrict__ centers) {
  int i = blockIdx.x * 256 + threadIdx.x;
  if (i < NXV) {
    float4 v = ((const float4*)x)[i];
    ushort4 o;
    o.x = f2bf(v.x); o.y = f2bf(v.y); o.z = f2bf(v.z); o.w = f2bf(v.w);
    ((ushort4*)xb)[i] = o;
    return;
  }
  i -= NXV;
  if (i < NWV) {
    float4 q = ((const float4*)Wq)[i];
    float4 k = ((const float4*)Wk)[i];
    float4 v = ((const float4*)Wv)[i];
    float4 o = ((const float4*)Wo)[i];
    ushort4 t;
    t.x = f2bf(q.x); t.y = f2bf(q.y); t.z = f2bf(q.z); t.w = f2bf(q.w);
    ((ushort4*)wcat)[i] = t;
    t.x = f2bf(k.x); t.y = f2bf(k.y); t.z = f2bf(k.z); t.w = f2bf(k.w);
    ((ushort4*)(wcat + NWE))[i] = t;
    t.x = f2bf(v.x); t.y = f2bf(v.y); t.z = f2bf(v.z); t.w = f2bf(v.w);
    ((ushort4*)(wcat + 2 * NWE))[i] = t;
    t.x = f2bf(o.x); t.y = f2bf(o.y); t.z = f2bf(o.z); t.w = f2bf(o.w);
    ((ushort4*)wob)[i] = t;
    return;
  }
  i -= NWV;
  if (i < NROWS) {
    float4 bx = ((const float4*)boxes)[i];
    centers[i] = make_float2((bx.x + bx.z) * 0.5f, (bx.y + bx.w) * 0.5f);
  }
}

// ---------------- NT GEMM: C[M,N] = A[M,K] * B[N,K]^T  (bf16 in, fp32 acc) ----
// BMxBN tile, 4 waves (2x2), 16x16x32 bf16 MFMA, double-buffered
// global_load_lds staging with explicit vmcnt drain (1 barrier per K-step).
template <int EPI, int BM, int BN>
__global__ __launch_bounds__(256, 2) void gemm_bt(
    const unsigned short* __restrict__ A, const unsigned short* __restrict__ Bw,
    int K, int tiles_n,
    const float* __restrict__ b0, const float* __restrict__ b1, const float* __restrict__ b2,
    unsigned short* __restrict__ outQ, unsigned short* __restrict__ outK,
    unsigned short* __restrict__ outVt, float* __restrict__ outF) {
  constexpr int MF = BM / 32, NF = BN / 32;
  __shared__ unsigned short lA[2][BM * 32];
  __shared__ unsigned short lB[2][BN * 32];
  const int tid = threadIdx.x, wave = tid >> 6, lane = tid & 63;
  const int tm = blockIdx.x / tiles_n, tn = blockIdx.x % tiles_n;
  const int wr = wave >> 1, wc = wave & 1;
  const int g = lane >> 4, c16 = lane & 15, kb8 = g * 8;

  f32x4 acc[MF][NF];
#pragma unroll
  for (int m = 0; m < MF; m++)
#pragma unroll
    for (int n = 0; n < NF; n++) acc[m][n] = (f32x4){0.f, 0.f, 0.f, 0.f};

  const unsigned short* Abase = A + (size_t)tm * BM * K;
  const unsigned short* Bbase = Bw + (size_t)tn * BN * K;
  const int srow = lane >> 2, scb = (lane & 3) << 4;

  auto stage = [&](int kt, int s) {
#pragma unroll
    for (int c = wave; c < BM / 16; c += 4)
      gload16((const char*)(Abase + (size_t)(c * 16 + srow) * K + kt) + scb,
              (char*)lA[s] + c * 1024);
#pragma unroll
    for (int c = wave; c < BN / 16; c += 4)
      gload16((const char*)(Bbase + (size_t)(c * 16 + srow) * K + kt) + scb,
              (char*)lB[s] + c * 1024);
  };

  stage(0, 0);
  const int nk = K >> 5;
#pragma unroll 1
  for (int i = 0; i < nk; i++) {
    drain_dma();
    __syncthreads();
    if (i + 1 < nk) stage((i + 1) * 32, (i + 1) & 1);
    const unsigned short* sA = lA[i & 1];
    const unsigned short* sB = lB[i & 1];
    short8 a[MF], b[NF];
#pragma unroll
    for (int m = 0; m < MF; m++)
      a[m] = *(const short8*)&sA[(wr * (BM / 2) + m * 16 + c16) * 32 + kb8];
#pragma unroll
    for (int n = 0; n < NF; n++)
      b[n] = *(const short8*)&sB[(wc * (BN / 2) + n * 16 + c16) * 32 + kb8];
#pragma unroll
    for (int m = 0; m < MF; m++)
#pragma unroll
      for (int n = 0; n < NF; n++)
        acc[m][n] = __builtin_amdgcn_mfma_f32_16x16x32_bf16(a[m], b[n], acc[m][n], 0, 0, 0);
  }

  // C/D layout (m89): col = lane&15, row = (lane>>4)*4 + r
#pragma unroll
  for (int m = 0; m < MF; m++) {
    const int gm0 = tm * BM + wr * (BM / 2) + m * 16 + g * 4;
    const int bb = gm0 >> 10, ss0 = gm0 & 1023;
#pragma unroll
    for (int n = 0; n < NF; n++) {
      const int gn = tn * BN + wc * (BN / 2) + n * 16 + c16;
      if (EPI == 0) {
        const int which = gn / DM, nn = gn - which * DM;
        const int h = nn >> 6, dh = nn & 63;
        const float bias = (which == 0 ? b0 : which == 1 ? b1 : b2)[nn];
        const float scale = (which == 0) ? 0.1803368801f : 1.0f;  // 0.125*log2e
        if (which == 2) {
          ushort4 pk;
          pk.x = f2bf(acc[m][n][0] + bias);
          pk.y = f2bf(acc[m][n][1] + bias);
          pk.z = f2bf(acc[m][n][2] + bias);
          pk.w = f2bf(acc[m][n][3] + bias);
          *(ushort4*)&outVt[(((size_t)bb * NHEADS + h) * HDIM + dh) * SQ + ss0] = pk;
        } else {
          unsigned short* dst = (which == 0 ? outQ : outK) + ((size_t)bb * NHEADS + h) * SQ * HDIM;
#pragma unroll
          for (int r = 0; r < 4; r++)
            dst[(size_t)(ss0 + r) * HDIM + dh] = f2bf((acc[m][n][r] + bias) * scale);
        }
      } else {
        const float bias = b0[gn];
#pragma unroll
        for (int r = 0; r < 4; r++)
          outF[(size_t)(gm0 + r) * DM + gn] = acc[m][n][r] + bias;
      }
    }
  }
}

// ---------------- fused spatial attention v7 (round-18 proven config) --------
// Swapped-operand flash, lane owns one q-row. KVB=64, K/V/cent double-buffered:
// per tile, ONE barrier + explicit vmcnt drain; stage(t+1) overlaps compute(t).
// XOR-swizzle on DMA source + LDS read (rule #21); hw cvt_pk bf16 packs.
// grid: 768 blocks = 48 bh * 16 qtiles (4 waves * 16 rows), XCD-swizzled.
#define KVB  64
#define NT   (SQ / KVB)  // 16 tiles
#define PSTR 72          // P row stride in shorts (64 + 8 pad)
__global__ __launch_bounds__(256, 3) void attn_kernel(
    const unsigned short* __restrict__ Qb, const unsigned short* __restrict__ Kb,
    const unsigned short* __restrict__ Vt, const float2* __restrict__ centers,
    const float* __restrict__ sbias, unsigned short* __restrict__ attb) {
  __shared__ unsigned short lK[2][KVB * HDIM];  // 2 x 8 KB, [64 rows][128 B] swizzled
  __shared__ unsigned short lV[2][HDIM * KVB];  // 2 x 8 KB, [64 rows][128 B] swizzled
  __shared__ float2 lcent[2][KVB];              // 2 x 512 B
  __shared__ unsigned short plds[4][16 * PSTR]; // 9216 B   (total 43008 -> 3 blk/CU)
  const int tid = threadIdx.x, wave = tid >> 6, lane = tid & 63;
  const int g = lane >> 4, c16 = lane & 15, kb8 = g * 8;
  const int bid = blockIdx.x;
  const int xcd = bid & 7, li = bid >> 3;       // li in 0..95
  const int bh = xcd * 6 + (li >> 4);
  const int qt = li & 15;
  const int b = bh / NHEADS, h = bh - b * NHEADS;
  const float sb = sbias[h] * 1.44269504f;      // exp2-domain bias coefficient

  const unsigned short* Qh = Qb + (size_t)bh * SQ * HDIM;
  const char* Kc = (const char*)(Kb + (size_t)bh * SQ * HDIM);  // K row = 128 B
  const char* Vc = (const char*)(Vt + (size_t)bh * HDIM * SQ);  // V row = 2048 B
  const float2* cent_g = centers + b * SQ;

  // staging lane terms (swizzle pre-applied to global source, rule #21)
  const int l8 = lane >> 3, l7 = lane & 7;      // 8 rows x 128 B per 1KB chunk
  const int swizL = (l7 * 16) ^ (l8 << 4);

  // stage one 64-token tile into buffer s: K 8 chunks, V 8 chunks (2/wave each)
  auto stage = [&](int tbn, int s) {
    const char* kbase = Kc + (size_t)tbn * 128;
#pragma unroll
    for (int j = 0; j < 2; j++) {
      const int i = wave * 2 + j;
      gload16(kbase + i * 1024 + l8 * 128 + swizL, (char*)lK[s] + i * 1024);
    }
    const char* vbase = Vc + (size_t)tbn * 2;
#pragma unroll
    for (int j = 0; j < 2; j++) {
      const int i = wave * 2 + j;
      gload16(vbase + (size_t)(i * 8 + l8) * 2048 + swizL, (char*)lV[s] + i * 1024);
    }
    if (tid < KVB) lcent[s][tid] = cent_g[tbn + tid];
  };

  const int q = qt * 64 + wave * 16 + c16;      // this lane's q-row
  short8 qf[2];
  qf[0] = *(const short8*)&Qh[(size_t)q * HDIM + kb8];
  qf[1] = *(const short8*)&Qh[(size_t)q * HDIM + 32 + kb8];
  const float2 cq = cent_g[q];

  float mreg = -1e30f, lreg = 0.f;              // lreg: per-lane partial sum
  f32x4 oacc[4];
#pragma unroll
  for (int dd = 0; dd < 4; dd++) oacc[dd] = (f32x4){0.f, 0.f, 0.f, 0.f};

  stage(0, 0);

  const int swk = (c16 & 7) << 4;               // read-side swizzle key
#pragma unroll 1
  for (int t = 0; t < NT; t++) {
    const int cur = t & 1;
    drain_dma();      // buf[cur] landed (all waves after barrier)
    __syncthreads();
    if (t + 1 < NT) stage((t + 1) * KVB, cur ^ 1);  // overlaps with compute
    // --- 1. QK^T from lK (swizzled b128 reads) ---
    f32x4 sv[4];
#pragma unroll
    for (int cc = 0; cc < 4; cc++) {
      const int rb = (cc * 16 + c16) * 128;
      short8 k0 = *(const short8*)((const char*)lK[cur] + rb + ((g * 16) ^ swk));
      short8 k1 = *(const short8*)((const char*)lK[cur] + rb + ((64 + g * 16) ^ swk));
      f32x4 s = (f32x4){0.f, 0.f, 0.f, 0.f};
      s = __builtin_amdgcn_mfma_f32_16x16x32_bf16(k0, qf[0], s, 0, 0, 0);
      s = __builtin_amdgcn_mfma_f32_16x16x32_bf16(k1, qf[1], s, 0, 0, 0);
      sv[cc] = s;
    }
    // --- 2. spatial bias from lcent (broadcast reads, raw v_sqrt) ---
#pragma unroll
    for (int cc = 0; cc < 4; cc++) {
      const float4* cp = (const float4*)&lcent[cur][cc * 16 + g * 4];
      float4 c01 = cp[0], c23 = cp[1];
      float dx, dy;
      dx = cq.x - c01.x; dy = cq.y - c01.y;
      sv[cc][0] -= __builtin_amdgcn_sqrtf(dx * dx + dy * dy) * sb;
      dx = cq.x - c01.z; dy = cq.y - c01.w;
      sv[cc][1] -= __builtin_amdgcn_sqrtf(dx * dx + dy * dy) * sb;
      dx = cq.x - c23.x; dy = cq.y - c23.y;
      sv[cc][2] -= __builtin_amdgcn_sqrtf(dx * dx + dy * dy) * sb;
      dx = cq.x - c23.z; dy = cq.y - c23.w;
      sv[cc][3] -= __builtin_amdgcn_sqrtf(dx * dx + dy * dy) * sb;
    }
    // --- 3. defer-max online softmax (no shfl in common path) ---
    float lm = -1e30f;
#pragma unroll
    for (int cc = 0; cc < 4; cc++) {
      float a0 = fmaxf(sv[cc][0], sv[cc][1]), a1 = fmaxf(sv[cc][2], sv[cc][3]);
      lm = fmaxf(lm, fmaxf(a0, a1));
    }
    if (!__all(lm <= mreg + 8.0f)) {
      float vmax = fmaxf(lm, __shfl_xor(lm, 16));
      vmax = fmaxf(vmax, __shfl_xor(vmax, 32));
      const float mn = fmaxf(mreg, vmax);
      const float sc = __builtin_amdgcn_exp2f(mreg - mn);
      lreg *= sc;
#pragma unroll
      for (int dd = 0; dd < 4; dd++)
#pragma unroll
        for (int r = 0; r < 4; r++) oacc[dd][r] *= sc;
      mreg = mn;
    }
    float ps = 0.f;
#pragma unroll
    for (int cc = 0; cc < 4; cc++)
#pragma unroll
      for (int r = 0; r < 4; r++) {
        sv[cc][r] = __builtin_amdgcn_exp2f(sv[cc][r] - mreg);
        ps += sv[cc][r];
      }
    lreg += ps;
    // --- 4. P -> per-wave LDS [q-row][token] (hw cvt_pk packs) ---
#pragma unroll
    for (int cc = 0; cc < 4; cc++) {
      uint2 u;
      u.x = pkbf(sv[cc][0], sv[cc][1]);
      u.y = pkbf(sv[cc][2], sv[cc][3]);
      *(uint2*)&plds[wave][c16 * PSTR + cc * 16 + g * 4] = u;
    }
    // --- 5. PV from lV (swizzled) + plds ---
#pragma unroll
    for (int kc = 0; kc < 2; kc++) {
      short8 pf = *(const short8*)&plds[wave][c16 * PSTR + kc * 32 + kb8];
#pragma unroll
      for (int dd = 0; dd < 4; dd++) {
        short8 vf = *(const short8*)((const char*)lV[cur] + (dd * 16 + c16) * 128 +
                                     ((kc * 64 + g * 16) ^ swk));
        oacc[dd] = __builtin_amdgcn_mfma_f32_16x16x32_bf16(vf, pf, oacc[dd], 0, 0, 0);
      }
    }
  }
  // --- epilogue: reduce l across the 4 row-group lanes, write O ---
  lreg += __shfl_xor(lreg, 16);
  lreg += __shfl_xor(lreg, 32);
  const float inv = 1.f / lreg;
#pragma unroll
  for (int dd = 0; dd < 4; dd++) {
    uint2 u;
    u.x = pkbf(oacc[dd][0] * inv, oacc[dd][1] * inv);
    u.y = pkbf(oacc[dd][2] * inv, oacc[dd][3] * inv);
    *(uint2*)&attb[(size_t)(b * SQ + q) * DM + h * HDIM + dd * 16 + g * 4] = u;
  }
}

// ---------------- host-side launch ----------------
extern "C" void kernel_launch(void* const* d_in, const int* in_sizes, int n_in,
                              void* d_out, int out_size, void* d_ws, size_t ws_size,
                              hipStream_t stream) {
  const float* x     = (const float*)d_in[0];
  const float* boxes = (const float*)d_in[1];
  const float* Wq    = (const float*)d_in[2];
  const float* bq    = (const float*)d_in[3];
  const float* Wk    = (const float*)d_in[4];
  const float* bk    = (const float*)d_in[5];
  const float* Wv    = (const float*)d_in[6];
  const float* bv    = (const float*)d_in[7];
  const float* Wo    = (const float*)d_in[8];
  const float* bo    = (const float*)d_in[9];
  const float* sb    = (const float*)d_in[10];

  char* ws = (char*)d_ws;
  unsigned short* xb   = (unsigned short*)(ws);             // 6291456 B
  unsigned short* wcat = (unsigned short*)(ws + 6291456);   // 3538944 B
  unsigned short* wob  = (unsigned short*)(ws + 9830400);   // 1179648 B
  unsigned short* qb   = (unsigned short*)(ws + 11010048);  // 6291456 B
  unsigned short* kb   = (unsigned short*)(ws + 17301504);  // 6291456 B
  unsigned short* vtb  = (unsigned short*)(ws + 23592960);  // 6291456 B
  unsigned short* attb = (unsigned short*)(ws + 29884416);  // 6291456 B
  float2* centers      = (float2*)(ws + 36175872);          // 32768 B  (total ~36.2 MB)
  float* out = (float*)d_out;

  // vectorized prep: (NXV + NWV + NROWS) / 256 = 937984/256 = 3664 blocks
  prep_kernel<<<3664, 256, 0, stream>>>(x, Wq, Wk, Wv, Wo, boxes, xb, wcat, wob, centers);
  // 128x96 tiles: N=2304=24x96 -> grid 32*24=768 = exactly 3 blocks/CU, balanced
  gemm_bt<0, 128, 96><<<32 * 24, 256, 0, stream>>>(xb, wcat, DM, 24, bq, bk, bv,
                                                   qb, kb, vtb, nullptr);
  attn_kernel<<<768, 256, 0, stream>>>(qb, kb, vtb, centers, sb, attb);
  gemm_bt<1, 64, 64><<<64 * 12, 256, 0, stream>>>(attb, wob, DM, 12, bo, nullptr, nullptr,
                                                  nullptr, nullptr, nullptr, out);
}